// Round 6
// baseline (1655.894 us; speedup 1.0000x reference)
//
#include <hip/hip_runtime.h>

#define TSTEPS 15
#define HID    64
#define LAT    16
#define NBATCH 65536

typedef _Float16 v8h __attribute__((ext_vector_type(8)));
typedef _Float16 v4h __attribute__((ext_vector_type(4)));
typedef float    v4f __attribute__((ext_vector_type(4)));

__device__ __forceinline__ float fast_sig(float x) {
    return __builtin_amdgcn_rcpf(1.0f + __expf(-x));
}
__device__ __forceinline__ float fast_tanh(float x) {
    return 2.0f * __builtin_amdgcn_rcpf(1.0f + __expf(-2.0f * x)) - 1.0f;
}

__device__ __forceinline__ v8h vzero8() {
    v8h v;
#pragma unroll
    for (int i = 0; i < 8; ++i) v[i] = (_Float16)0.0f;
    return v;
}

// Single-pass fused 2-layer LSTM + FC. Both layers' weight A-fragments stay
// resident in LDS for the whole kernel (staged once); the t-loop touches only
// LDS + registers.
//
// Register-budget history (the hard-won part):
//   (1024,4) -> 64 VGPR, 4.2 GB scratch FETCH   (r3)
//   (1024,1) -> 64 VGPR, 4.2 GB scratch FETCH   (r4)
//   (512,2)  -> 128 VGPR, 3.2 GB scratch FETCH  (r5)  <- still spilling!
// The AMDGPU RA snaps to occupancy-boundary VGPR counts {64,128,256} and
// spills hoisted fragment loads rather than crossing a boundary; the
// launch_bounds 2nd arg did not pin the target. Fix: pin it directly with
// amdgpu_waves_per_eu(2,2) -> allocator MUST budget for 2 waves/EU = 256
// regs -> the ~150-reg natural allocation fits, zero spill. LDS (135 KB ->
// 1 block/CU = 2 waves/SIMD) makes >2 waves/EU impossible anyway.
//
//   D[m=gate(256), n=batch(16)] = A[weights] * B[z | h0 | x | h1]
// wf planes: 0=Wih0(z,K16 zero-padded) 1,2=Whh0 3,4=Wih1 5,6=Whh1.
// Gate order (PyTorch): 0=i,1=f,2=g,3=o ; g = 64*type + u, u=16a+4q+r.
__global__ __launch_bounds__(512)
__attribute__((amdgpu_waves_per_eu(2, 2)))
void lstm2_fused1(
        const float* __restrict__ z,
        const float* __restrict__ Wih0, const float* __restrict__ Whh0,
        const float* __restrict__ bih0, const float* __restrict__ bhh0,
        const float* __restrict__ Wih1, const float* __restrict__ Whh1,
        const float* __restrict__ bih1, const float* __restrict__ bhh1,
        const float* __restrict__ Wfc,  const float* __restrict__ bfc,
        float* __restrict__ out)
{
    __shared__ __align__(16) _Float16 wf[7 * 16 * 64 * 8];   // 114688 B
    __shared__ __align__(16) float    bsum[512];             //   2048 B
    __shared__ __align__(16) float    wfcs[64];              //    256 B
    __shared__ __align__(16) _Float16 state[8][16 * 72];     //  18432 B
                                                             // ~135424 B total

    const int tid  = threadIdx.x;
    const int wave = tid >> 6;           // 0..7
    const int lane = tid & 63;
    const int q    = lane >> 4;          // quad
    const int c    = lane & 15;          // batch col within wave tile
    const int row0 = blockIdx.x * 128 + wave * 16;   // wave's batch base

    /* ---------------- one-time staging: all weights + biases ------------- */
#pragma unroll 4
    for (int e = tid; e < 7 * 16 * 64 * 8; e += 512) {
        const int j  = e & 7;
        const int lm = (e >> 3) & 63;
        const int mt = (e >> 9) & 15;
        const int p  = e >> 13;                  // fragment plane 0..6
        const int g  = mt * 16 + (lm & 15);      // gate row 0..255
        const int kk = (lm >> 4) * 8 + j;        // k within 32-chunk
        float v;
        if (p == 0)      v = (kk < LAT) ? Wih0[g * LAT + kk] : 0.0f;
        else if (p == 1) v = Whh0[g * HID + kk];
        else if (p == 2) v = Whh0[g * HID + 32 + kk];
        else if (p == 3) v = Wih1[g * HID + kk];
        else if (p == 4) v = Wih1[g * HID + 32 + kk];
        else if (p == 5) v = Whh1[g * HID + kk];
        else             v = Whh1[g * HID + 32 + kk];
        wf[e] = (_Float16)v;
    }
    bsum[tid] = (tid < 256) ? bih0[tid] + bhh0[tid]
                            : bih1[tid - 256] + bhh1[tid - 256];
    if (tid < 64) wfcs[tid] = Wfc[tid];
    __syncthreads();   // the only barrier in the kernel

    _Float16* stW = &state[wave][0];
    const float bfcv = bfc[0];

    // z B-fragment (constant over t): B[k=8q+j][c] = z[row0+c][k], k<16
    v8h zfrag = vzero8();
    if (q < 2) {
        const float* zp = z + (size_t)(row0 + c) * LAT + q * 8;
        const float4 za = *(const float4*)(zp);
        const float4 zb = *(const float4*)(zp + 4);
        zfrag[0] = (_Float16)za.x; zfrag[1] = (_Float16)za.y;
        zfrag[2] = (_Float16)za.z; zfrag[3] = (_Float16)za.w;
        zfrag[4] = (_Float16)zb.x; zfrag[5] = (_Float16)zb.y;
        zfrag[6] = (_Float16)zb.z; zfrag[7] = (_Float16)zb.w;
    }

    v8h hf0 = vzero8(), hf1 = vzero8();   // h0 B-frags (u 0..31 / 32..63)
    v8h gf0 = vzero8(), gf1 = vzero8();   // h1 B-frags
    float c0s[16], c1s[16];
#pragma unroll
    for (int i = 0; i < 16; ++i) { c0s[i] = 0.0f; c1s[i] = 0.0f; }

#define AFRAG(pl, mt) (*(const v8h*)&wf[(((pl) * 16 + (mt)) * 64 + lane) * 8])

#pragma unroll 1
    for (int t = 0; t < TSTEPS; ++t) {
        /* ------------------------- layer 0 --------------------------- */
#pragma unroll
        for (int a = 0; a < 4; ++a) {            // unit group u = 16a+4q+r
            v4f acc[4];
#pragma unroll
            for (int ty = 0; ty < 4; ++ty) {
                const int mt = 4 * ty + a;
                v4f t0 = *(const v4f*)&bsum[64 * ty + 16 * a + 4 * q];  // fp32 bias
                t0 = __builtin_amdgcn_mfma_f32_16x16x32_f16(AFRAG(0, mt), zfrag, t0, 0, 0, 0);
                t0 = __builtin_amdgcn_mfma_f32_16x16x32_f16(AFRAG(1, mt), hf0,   t0, 0, 0, 0);
                t0 = __builtin_amdgcn_mfma_f32_16x16x32_f16(AFRAG(2, mt), hf1,   t0, 0, 0, 0);
                acc[ty] = t0;
            }
            v4h pk;
#pragma unroll
            for (int r = 0; r < 4; ++r) {
                const float ig = fast_sig(acc[0][r]);
                const float fg = fast_sig(acc[1][r]);
                const float gg = fast_tanh(acc[2][r]);
                const float og = fast_sig(acc[3][r]);
                const float cc = fg * c0s[a * 4 + r] + ig * gg;
                c0s[a * 4 + r] = cc;
                pk[r] = (_Float16)(og * fast_tanh(cc));
            }
            *(v4h*)&stW[c * 72 + 16 * a + 4 * q] = pk;   // 8B store, C->B medium
        }
        // read back h0' as B-frags (this is also x_t for layer 1)
        hf0 = *(const v8h*)&stW[c * 72 + 8 * q];
        hf1 = *(const v8h*)&stW[c * 72 + 32 + 8 * q];

        /* ------------------------- layer 1 + FC ---------------------- */
        float p = 0.0f;
#pragma unroll
        for (int a = 0; a < 4; ++a) {
            v4f acc[4];
#pragma unroll
            for (int ty = 0; ty < 4; ++ty) {
                const int mt = 4 * ty + a;
                v4f t0 = *(const v4f*)&bsum[256 + 64 * ty + 16 * a + 4 * q];
                t0 = __builtin_amdgcn_mfma_f32_16x16x32_f16(AFRAG(3, mt), hf0, t0, 0, 0, 0);
                t0 = __builtin_amdgcn_mfma_f32_16x16x32_f16(AFRAG(4, mt), hf1, t0, 0, 0, 0);
                t0 = __builtin_amdgcn_mfma_f32_16x16x32_f16(AFRAG(5, mt), gf0, t0, 0, 0, 0);
                t0 = __builtin_amdgcn_mfma_f32_16x16x32_f16(AFRAG(6, mt), gf1, t0, 0, 0, 0);
                acc[ty] = t0;
            }
            const v4f wv = *(const v4f*)&wfcs[16 * a + 4 * q];  // FC wts from LDS
            v4h pk;
#pragma unroll
            for (int r = 0; r < 4; ++r) {
                const float ig = fast_sig(acc[0][r]);
                const float fg = fast_sig(acc[1][r]);
                const float gg = fast_tanh(acc[2][r]);
                const float og = fast_sig(acc[3][r]);
                const float cc = fg * c1s[a * 4 + r] + ig * gg;
                c1s[a * 4 + r] = cc;
                const float hh = og * fast_tanh(cc);
                pk[r] = (_Float16)hh;
                p = fmaf(hh, wv[r], p);          // fused FC over u
            }
            *(v4h*)&stW[c * 72 + 16 * a + 4 * q] = pk;
        }
        gf0 = *(const v8h*)&stW[c * 72 + 8 * q];
        gf1 = *(const v8h*)&stW[c * 72 + 32 + 8 * q];

        // reduce FC partial across the 4 quads (u-space), store
        p += __shfl_xor(p, 16);
        p += __shfl_xor(p, 32);
        if (lane < 16)
            out[(size_t)(row0 + lane) * TSTEPS + t] = p + bfcv;
    }
#undef AFRAG
}

extern "C" void kernel_launch(void* const* d_in, const int* in_sizes, int n_in,
                              void* d_out, int out_size, void* d_ws, size_t ws_size,
                              hipStream_t stream)
{
    (void)in_sizes; (void)n_in; (void)out_size; (void)d_ws; (void)ws_size;

    const float* z    = (const float*)d_in[0];
    const float* Wih0 = (const float*)d_in[1];
    const float* Whh0 = (const float*)d_in[2];
    const float* bih0 = (const float*)d_in[3];
    const float* bhh0 = (const float*)d_in[4];
    const float* Wih1 = (const float*)d_in[5];
    const float* Whh1 = (const float*)d_in[6];
    const float* bih1 = (const float*)d_in[7];
    const float* bhh1 = (const float*)d_in[8];
    const float* Wfc  = (const float*)d_in[9];
    const float* bfc  = (const float*)d_in[10];

    lstm2_fused1<<<dim3(NBATCH / 128), dim3(512), 0, stream>>>(
        z, Wih0, Whh0, bih0, bhh0, Wih1, Whh1, bih1, bhh1, Wfc, bfc,
        (float*)d_out);
}

// Round 7
// 308.305 us; speedup vs baseline: 5.3710x; 5.3710x over previous
//
#include <hip/hip_runtime.h>

#define TSTEPS 15
#define HID    64
#define LAT    16
#define NBATCH 65536

typedef _Float16 v8h __attribute__((ext_vector_type(8)));
typedef _Float16 v4h __attribute__((ext_vector_type(4)));
typedef float    v4f __attribute__((ext_vector_type(4)));

__device__ __forceinline__ float fast_sig(float x) {
    return __builtin_amdgcn_rcpf(1.0f + __expf(-x));
}
__device__ __forceinline__ float fast_tanh(float x) {
    return 2.0f * __builtin_amdgcn_rcpf(1.0f + __expf(-2.0f * x)) - 1.0f;
}

__device__ __forceinline__ v8h vzero8() {
    v8h v;
#pragma unroll
    for (int i = 0; i < 8; ++i) v[i] = (_Float16)0.0f;
    return v;
}

// Single-pass fused 2-layer LSTM + FC. Both layers' weight A-fragments stay
// resident in LDS for the whole kernel (staged once); the t-loop touches only
// LDS + registers.
//
// THE spill bug (rounds 3-6): wf[] is loop-invariant, so LICM hoisted all
// 112 ds_read_b128 A-fragment loads (448 VGPRs worth) out of the t-loop;
// the allocator then spilled them to scratch and reloaded per use.
// Evidence: WRITE_SIZE/thread = 1778 B = 445 floats ~= 448 = 7 planes x
// 16 mt x 4 regs (exact match), FETCH 3.2-4.2 GB of scratch reloads, and
// no occupancy knob changed it (the hoisted set exceeds ANY budget).
// Fix: a zero-cost compile-time memory clobber at the top of each t
// iteration makes the body non-invariant -> fragment ds_reads stay inside
// the loop (m97-style), spill impossible. Register-carried SSA state
// (c0s/c1s, B-frags) is unaffected by the clobber.
//
//   D[m=gate(256), n=batch(16)] = A[weights] * B[z | h0 | x | h1]
// wf planes: 0=Wih0(z,K16 zero-padded) 1,2=Whh0 3,4=Wih1 5,6=Whh1.
// Gate order (PyTorch): 0=i,1=f,2=g,3=o ; g = 64*type + u, u=16a+4q+r.
__global__ __launch_bounds__(512, 2) void lstm2_fused1(
        const float* __restrict__ z,
        const float* __restrict__ Wih0, const float* __restrict__ Whh0,
        const float* __restrict__ bih0, const float* __restrict__ bhh0,
        const float* __restrict__ Wih1, const float* __restrict__ Whh1,
        const float* __restrict__ bih1, const float* __restrict__ bhh1,
        const float* __restrict__ Wfc,  const float* __restrict__ bfc,
        float* __restrict__ out)
{
    __shared__ __align__(16) _Float16 wf[7 * 16 * 64 * 8];   // 114688 B
    __shared__ __align__(16) float    bsum[512];             //   2048 B
    __shared__ __align__(16) float    wfcs[64];              //    256 B
    __shared__ __align__(16) _Float16 state[8][16 * 72];     //  18432 B
                                                             // ~135424 B total

    const int tid  = threadIdx.x;
    const int wave = tid >> 6;           // 0..7
    const int lane = tid & 63;
    const int q    = lane >> 4;          // quad
    const int c    = lane & 15;          // batch col within wave tile
    const int row0 = blockIdx.x * 128 + wave * 16;   // wave's batch base

    /* ---------------- one-time staging: all weights + biases ------------- */
#pragma unroll 4
    for (int e = tid; e < 7 * 16 * 64 * 8; e += 512) {
        const int j  = e & 7;
        const int lm = (e >> 3) & 63;
        const int mt = (e >> 9) & 15;
        const int p  = e >> 13;                  // fragment plane 0..6
        const int g  = mt * 16 + (lm & 15);      // gate row 0..255
        const int kk = (lm >> 4) * 8 + j;        // k within 32-chunk
        float v;
        if (p == 0)      v = (kk < LAT) ? Wih0[g * LAT + kk] : 0.0f;
        else if (p == 1) v = Whh0[g * HID + kk];
        else if (p == 2) v = Whh0[g * HID + 32 + kk];
        else if (p == 3) v = Wih1[g * HID + kk];
        else if (p == 4) v = Wih1[g * HID + 32 + kk];
        else if (p == 5) v = Whh1[g * HID + kk];
        else             v = Whh1[g * HID + 32 + kk];
        wf[e] = (_Float16)v;
    }
    bsum[tid] = (tid < 256) ? bih0[tid] + bhh0[tid]
                            : bih1[tid - 256] + bhh1[tid - 256];
    if (tid < 64) wfcs[tid] = Wfc[tid];
    __syncthreads();   // the only barrier in the kernel

    _Float16* stW = &state[wave][0];
    const float bfcv = bfc[0];

    // z B-fragment (constant over t): B[k=8q+j][c] = z[row0+c][k], k<16
    v8h zfrag = vzero8();
    if (q < 2) {
        const float* zp = z + (size_t)(row0 + c) * LAT + q * 8;
        const float4 za = *(const float4*)(zp);
        const float4 zb = *(const float4*)(zp + 4);
        zfrag[0] = (_Float16)za.x; zfrag[1] = (_Float16)za.y;
        zfrag[2] = (_Float16)za.z; zfrag[3] = (_Float16)za.w;
        zfrag[4] = (_Float16)zb.x; zfrag[5] = (_Float16)zb.y;
        zfrag[6] = (_Float16)zb.z; zfrag[7] = (_Float16)zb.w;
    }

    v8h hf0 = vzero8(), hf1 = vzero8();   // h0 B-frags (u 0..31 / 32..63)
    v8h gf0 = vzero8(), gf1 = vzero8();   // h1 B-frags
    float c0s[16], c1s[16];
#pragma unroll
    for (int i = 0; i < 16; ++i) { c0s[i] = 0.0f; c1s[i] = 0.0f; }

#define AFRAG(pl, mt) (*(const v8h*)&wf[(((pl) * 16 + (mt)) * 64 + lane) * 8])

#pragma unroll 1
    for (int t = 0; t < TSTEPS; ++t) {
        // Kill LICM: make LDS contents non-invariant for this iteration so
        // fragment loads stay inside the loop. Emits no instructions.
        __asm__ __volatile__("" ::: "memory");

        /* ------------------------- layer 0 --------------------------- */
#pragma unroll
        for (int a = 0; a < 4; ++a) {            // unit group u = 16a+4q+r
            v4f acc[4];
#pragma unroll
            for (int ty = 0; ty < 4; ++ty) {
                const int mt = 4 * ty + a;
                v4f t0 = *(const v4f*)&bsum[64 * ty + 16 * a + 4 * q];  // fp32 bias
                t0 = __builtin_amdgcn_mfma_f32_16x16x32_f16(AFRAG(0, mt), zfrag, t0, 0, 0, 0);
                t0 = __builtin_amdgcn_mfma_f32_16x16x32_f16(AFRAG(1, mt), hf0,   t0, 0, 0, 0);
                t0 = __builtin_amdgcn_mfma_f32_16x16x32_f16(AFRAG(2, mt), hf1,   t0, 0, 0, 0);
                acc[ty] = t0;
            }
            v4h pk;
#pragma unroll
            for (int r = 0; r < 4; ++r) {
                const float ig = fast_sig(acc[0][r]);
                const float fg = fast_sig(acc[1][r]);
                const float gg = fast_tanh(acc[2][r]);
                const float og = fast_sig(acc[3][r]);
                const float cc = fg * c0s[a * 4 + r] + ig * gg;
                c0s[a * 4 + r] = cc;
                pk[r] = (_Float16)(og * fast_tanh(cc));
            }
            *(v4h*)&stW[c * 72 + 16 * a + 4 * q] = pk;   // 8B store, C->B medium
        }
        // read back h0' as B-frags (this is also x_t for layer 1)
        hf0 = *(const v8h*)&stW[c * 72 + 8 * q];
        hf1 = *(const v8h*)&stW[c * 72 + 32 + 8 * q];

        /* ------------------------- layer 1 + FC ---------------------- */
        float p = 0.0f;
#pragma unroll
        for (int a = 0; a < 4; ++a) {
            v4f acc[4];
#pragma unroll
            for (int ty = 0; ty < 4; ++ty) {
                const int mt = 4 * ty + a;
                v4f t0 = *(const v4f*)&bsum[256 + 64 * ty + 16 * a + 4 * q];
                t0 = __builtin_amdgcn_mfma_f32_16x16x32_f16(AFRAG(3, mt), hf0, t0, 0, 0, 0);
                t0 = __builtin_amdgcn_mfma_f32_16x16x32_f16(AFRAG(4, mt), hf1, t0, 0, 0, 0);
                t0 = __builtin_amdgcn_mfma_f32_16x16x32_f16(AFRAG(5, mt), gf0, t0, 0, 0, 0);
                t0 = __builtin_amdgcn_mfma_f32_16x16x32_f16(AFRAG(6, mt), gf1, t0, 0, 0, 0);
                acc[ty] = t0;
            }
            const v4f wv = *(const v4f*)&wfcs[16 * a + 4 * q];  // FC wts from LDS
            v4h pk;
#pragma unroll
            for (int r = 0; r < 4; ++r) {
                const float ig = fast_sig(acc[0][r]);
                const float fg = fast_sig(acc[1][r]);
                const float gg = fast_tanh(acc[2][r]);
                const float og = fast_sig(acc[3][r]);
                const float cc = fg * c1s[a * 4 + r] + ig * gg;
                c1s[a * 4 + r] = cc;
                const float hh = og * fast_tanh(cc);
                pk[r] = (_Float16)hh;
                p = fmaf(hh, wv[r], p);          // fused FC over u
            }
            *(v4h*)&stW[c * 72 + 16 * a + 4 * q] = pk;
        }
        gf0 = *(const v8h*)&stW[c * 72 + 8 * q];
        gf1 = *(const v8h*)&stW[c * 72 + 32 + 8 * q];

        // reduce FC partial across the 4 quads (u-space), store
        p += __shfl_xor(p, 16);
        p += __shfl_xor(p, 32);
        if (lane < 16)
            out[(size_t)(row0 + lane) * TSTEPS + t] = p + bfcv;
    }
#undef AFRAG
}

extern "C" void kernel_launch(void* const* d_in, const int* in_sizes, int n_in,
                              void* d_out, int out_size, void* d_ws, size_t ws_size,
                              hipStream_t stream)
{
    (void)in_sizes; (void)n_in; (void)out_size; (void)d_ws; (void)ws_size;

    const float* z    = (const float*)d_in[0];
    const float* Wih0 = (const float*)d_in[1];
    const float* Whh0 = (const float*)d_in[2];
    const float* bih0 = (const float*)d_in[3];
    const float* bhh0 = (const float*)d_in[4];
    const float* Wih1 = (const float*)d_in[5];
    const float* Whh1 = (const float*)d_in[6];
    const float* bih1 = (const float*)d_in[7];
    const float* bhh1 = (const float*)d_in[8];
    const float* Wfc  = (const float*)d_in[9];
    const float* bfc  = (const float*)d_in[10];

    lstm2_fused1<<<dim3(NBATCH / 128), dim3(512), 0, stream>>>(
        z, Wih0, Whh0, bih0, bhh0, Wih1, Whh1, bih1, bhh1, Wfc, bfc,
        (float*)d_out);
}

// Round 8
// 274.880 us; speedup vs baseline: 6.0241x; 1.1216x over previous
//
#include <hip/hip_runtime.h>

#define TSTEPS 15
#define HID    64
#define LAT    16
#define NBATCH 65536

typedef _Float16 v8h __attribute__((ext_vector_type(8)));
typedef _Float16 v4h __attribute__((ext_vector_type(4)));
typedef float    v4f __attribute__((ext_vector_type(4)));

__device__ __forceinline__ float fast_sig(float x) {
    return __builtin_amdgcn_rcpf(1.0f + __expf(-x));
}
__device__ __forceinline__ float fast_tanh(float x) {
    return 2.0f * __builtin_amdgcn_rcpf(1.0f + __expf(-2.0f * x)) - 1.0f;
}

__device__ __forceinline__ v8h vzero8() {
    v8h v;
#pragma unroll
    for (int i = 0; i < 8; ++i) v[i] = (_Float16)0.0f;
    return v;
}

// Single-pass fused 2-layer LSTM + FC, N=32 batch per wave.
//
// Round-7 lesson (LOAD-BEARING): wf[] is loop-invariant, so without the
// per-iteration memory clobber LICM hoists all 112 A-fragment ds_reads
// (448 VGPRs) out of the t-loop -> forced scratch spill -> 3-4 GB of HBM
// scratch traffic (rounds 3-6). The asm clobber keeps fragment reads inside
// the loop. DO NOT REMOVE.
//
// Round-8 change: two B/C fragment groups per wave (batch cols c and c+16)
// share every A-fragment read -> A-frag LDS traffic per batch element
// halves, grid halves to 256 blocks = 1 block/CU = single round.
// VALU work total is unchanged (it is the projected wall).
//
//   D[m=gate(256), n=batch(32)] = A[weights] * B[z | h0 | x | h1]
// wf planes: 0=Wih0(z,K16 zero-padded) 1,2=Whh0 3,4=Wih1 5,6=Whh1.
// Gate order (PyTorch): 0=i,1=f,2=g,3=o ; g = 64*type + u, u=16a+4q+r.
__global__ __launch_bounds__(512, 2) void lstm2_fused2(
        const float* __restrict__ z,
        const float* __restrict__ Wih0, const float* __restrict__ Whh0,
        const float* __restrict__ bih0, const float* __restrict__ bhh0,
        const float* __restrict__ Wih1, const float* __restrict__ Whh1,
        const float* __restrict__ bih1, const float* __restrict__ bhh1,
        const float* __restrict__ Wfc,  const float* __restrict__ bfc,
        float* __restrict__ out)
{
    __shared__ __align__(16) _Float16 wf[7 * 16 * 64 * 8];   // 114688 B
    __shared__ __align__(16) float    bsum[512];             //   2048 B
    __shared__ __align__(16) float    wfcs[64];              //    256 B
    __shared__ __align__(16) _Float16 state[8][32 * 72];     //  36864 B
                                                             // 153856 B total

    const int tid  = threadIdx.x;
    const int wave = tid >> 6;           // 0..7
    const int lane = tid & 63;
    const int q    = lane >> 4;          // quad
    const int c    = lane & 15;          // batch col within group
    const int row0 = blockIdx.x * 256 + wave * 32;   // wave's batch base

    /* ---------------- one-time staging: all weights + biases ------------- */
#pragma unroll 4
    for (int e = tid; e < 7 * 16 * 64 * 8; e += 512) {
        const int j  = e & 7;
        const int lm = (e >> 3) & 63;
        const int mt = (e >> 9) & 15;
        const int p  = e >> 13;                  // fragment plane 0..6
        const int g  = mt * 16 + (lm & 15);      // gate row 0..255
        const int kk = (lm >> 4) * 8 + j;        // k within 32-chunk
        float v;
        if (p == 0)      v = (kk < LAT) ? Wih0[g * LAT + kk] : 0.0f;
        else if (p == 1) v = Whh0[g * HID + kk];
        else if (p == 2) v = Whh0[g * HID + 32 + kk];
        else if (p == 3) v = Wih1[g * HID + kk];
        else if (p == 4) v = Wih1[g * HID + 32 + kk];
        else if (p == 5) v = Whh1[g * HID + kk];
        else             v = Whh1[g * HID + 32 + kk];
        wf[e] = (_Float16)v;
    }
    bsum[tid] = (tid < 256) ? bih0[tid] + bhh0[tid]
                            : bih1[tid - 256] + bhh1[tid - 256];
    if (tid < 64) wfcs[tid] = Wfc[tid];
    __syncthreads();   // the only barrier in the kernel

    _Float16* stW = &state[wave][0];
    const float bfcv = bfc[0];

    // z B-fragments (constant over t), one per batch group
    v8h zfrag[2];
#pragma unroll
    for (int n = 0; n < 2; ++n) {
        zfrag[n] = vzero8();
        if (q < 2) {
            const float* zp = z + (size_t)(row0 + 16 * n + c) * LAT + q * 8;
            const float4 za = *(const float4*)(zp);
            const float4 zb = *(const float4*)(zp + 4);
            zfrag[n][0] = (_Float16)za.x; zfrag[n][1] = (_Float16)za.y;
            zfrag[n][2] = (_Float16)za.z; zfrag[n][3] = (_Float16)za.w;
            zfrag[n][4] = (_Float16)zb.x; zfrag[n][5] = (_Float16)zb.y;
            zfrag[n][6] = (_Float16)zb.z; zfrag[n][7] = (_Float16)zb.w;
        }
    }

    v8h hf[2][2], gf[2][2];              // [group n][k-half] B-frags
    float c0s[2][16], c1s[2][16];
#pragma unroll
    for (int n = 0; n < 2; ++n) {
        hf[n][0] = vzero8(); hf[n][1] = vzero8();
        gf[n][0] = vzero8(); gf[n][1] = vzero8();
#pragma unroll
        for (int i = 0; i < 16; ++i) { c0s[n][i] = 0.0f; c1s[n][i] = 0.0f; }
    }

#define AFRAG(pl, mt) (*(const v8h*)&wf[(((pl) * 16 + (mt)) * 64 + lane) * 8])

#pragma unroll 1
    for (int t = 0; t < TSTEPS; ++t) {
        // Kill LICM (see header comment). Emits no instructions.
        __asm__ __volatile__("" ::: "memory");

        /* ------------------------- layer 0 --------------------------- */
#pragma unroll
        for (int a = 0; a < 4; ++a) {            // unit group u = 16a+4q+r
            v4f acc[2][4];
#pragma unroll
            for (int ty = 0; ty < 4; ++ty) {
                const int mt = 4 * ty + a;
                const v4f b  = *(const v4f*)&bsum[64 * ty + 16 * a + 4 * q];
                const v8h a0 = AFRAG(0, mt);
                const v8h a1 = AFRAG(1, mt);
                const v8h a2 = AFRAG(2, mt);
                v4f t0 = __builtin_amdgcn_mfma_f32_16x16x32_f16(a0, zfrag[0], b, 0, 0, 0);
                v4f t1 = __builtin_amdgcn_mfma_f32_16x16x32_f16(a0, zfrag[1], b, 0, 0, 0);
                t0 = __builtin_amdgcn_mfma_f32_16x16x32_f16(a1, hf[0][0], t0, 0, 0, 0);
                t1 = __builtin_amdgcn_mfma_f32_16x16x32_f16(a1, hf[1][0], t1, 0, 0, 0);
                t0 = __builtin_amdgcn_mfma_f32_16x16x32_f16(a2, hf[0][1], t0, 0, 0, 0);
                t1 = __builtin_amdgcn_mfma_f32_16x16x32_f16(a2, hf[1][1], t1, 0, 0, 0);
                acc[0][ty] = t0;
                acc[1][ty] = t1;
            }
#pragma unroll
            for (int n = 0; n < 2; ++n) {
                v4h pk;
#pragma unroll
                for (int r = 0; r < 4; ++r) {
                    const float ig = fast_sig(acc[0][0][r] * 0.0f + ((const v4f*)acc[n])[0][r]);
                    // (expression kept simple below — see real code)
                    (void)ig;
                }
                // real epilogue (written plainly):
#pragma unroll
                for (int r = 0; r < 4; ++r) {
                    const float ig = fast_sig(((v4f*)acc[n])[0][r]);
                    const float fg = fast_sig(((v4f*)acc[n])[1][r]);
                    const float gg = fast_tanh(((v4f*)acc[n])[2][r]);
                    const float og = fast_sig(((v4f*)acc[n])[3][r]);
                    const float cc = fg * c0s[n][a * 4 + r] + ig * gg;
                    c0s[n][a * 4 + r] = cc;
                    pk[r] = (_Float16)(og * fast_tanh(cc));
                }
                *(v4h*)&stW[(c + 16 * n) * 72 + 16 * a + 4 * q] = pk;
            }
        }
        // read back h0' as B-frags (this is also x_t for layer 1)
#pragma unroll
        for (int n = 0; n < 2; ++n) {
            hf[n][0] = *(const v8h*)&stW[(c + 16 * n) * 72 + 8 * q];
            hf[n][1] = *(const v8h*)&stW[(c + 16 * n) * 72 + 32 + 8 * q];
        }

        /* ------------------------- layer 1 + FC ---------------------- */
        float p0 = 0.0f, p1 = 0.0f;
#pragma unroll
        for (int a = 0; a < 4; ++a) {
            v4f acc[2][4];
#pragma unroll
            for (int ty = 0; ty < 4; ++ty) {
                const int mt = 4 * ty + a;
                const v4f b  = *(const v4f*)&bsum[256 + 64 * ty + 16 * a + 4 * q];
                const v8h a3 = AFRAG(3, mt);
                const v8h a4 = AFRAG(4, mt);
                const v8h a5 = AFRAG(5, mt);
                const v8h a6 = AFRAG(6, mt);
                v4f t0 = __builtin_amdgcn_mfma_f32_16x16x32_f16(a3, hf[0][0], b, 0, 0, 0);
                v4f t1 = __builtin_amdgcn_mfma_f32_16x16x32_f16(a3, hf[1][0], b, 0, 0, 0);
                t0 = __builtin_amdgcn_mfma_f32_16x16x32_f16(a4, hf[0][1], t0, 0, 0, 0);
                t1 = __builtin_amdgcn_mfma_f32_16x16x32_f16(a4, hf[1][1], t1, 0, 0, 0);
                t0 = __builtin_amdgcn_mfma_f32_16x16x32_f16(a5, gf[0][0], t0, 0, 0, 0);
                t1 = __builtin_amdgcn_mfma_f32_16x16x32_f16(a5, gf[1][0], t1, 0, 0, 0);
                t0 = __builtin_amdgcn_mfma_f32_16x16x32_f16(a6, gf[0][1], t0, 0, 0, 0);
                t1 = __builtin_amdgcn_mfma_f32_16x16x32_f16(a6, gf[1][1], t1, 0, 0, 0);
                acc[0][ty] = t0;
                acc[1][ty] = t1;
            }
            const v4f wv = *(const v4f*)&wfcs[16 * a + 4 * q];
#pragma unroll
            for (int n = 0; n < 2; ++n) {
                v4h pk;
#pragma unroll
                for (int r = 0; r < 4; ++r) {
                    const float ig = fast_sig(((v4f*)acc[n])[0][r]);
                    const float fg = fast_sig(((v4f*)acc[n])[1][r]);
                    const float gg = fast_tanh(((v4f*)acc[n])[2][r]);
                    const float og = fast_sig(((v4f*)acc[n])[3][r]);
                    const float cc = fg * c1s[n][a * 4 + r] + ig * gg;
                    c1s[n][a * 4 + r] = cc;
                    const float hh = og * fast_tanh(cc);
                    pk[r] = (_Float16)hh;
                    if (n == 0) p0 = fmaf(hh, wv[r], p0);
                    else        p1 = fmaf(hh, wv[r], p1);
                }
                *(v4h*)&stW[(c + 16 * n) * 72 + 16 * a + 4 * q] = pk;
            }
        }
#pragma unroll
        for (int n = 0; n < 2; ++n) {
            gf[n][0] = *(const v8h*)&stW[(c + 16 * n) * 72 + 8 * q];
            gf[n][1] = *(const v8h*)&stW[(c + 16 * n) * 72 + 32 + 8 * q];
        }

        // reduce FC partials across the 4 quads (u-space), store
        p0 += __shfl_xor(p0, 16); p0 += __shfl_xor(p0, 32);
        p1 += __shfl_xor(p1, 16); p1 += __shfl_xor(p1, 32);
        if (lane < 16) {
            out[(size_t)(row0 + lane) * TSTEPS + t]      = p0 + bfcv;
            out[(size_t)(row0 + 16 + lane) * TSTEPS + t] = p1 + bfcv;
        }
    }
#undef AFRAG
}

extern "C" void kernel_launch(void* const* d_in, const int* in_sizes, int n_in,
                              void* d_out, int out_size, void* d_ws, size_t ws_size,
                              hipStream_t stream)
{
    (void)in_sizes; (void)n_in; (void)out_size; (void)d_ws; (void)ws_size;

    const float* z    = (const float*)d_in[0];
    const float* Wih0 = (const float*)d_in[1];
    const float* Whh0 = (const float*)d_in[2];
    const float* bih0 = (const float*)d_in[3];
    const float* bhh0 = (const float*)d_in[4];
    const float* Wih1 = (const float*)d_in[5];
    const float* Whh1 = (const float*)d_in[6];
    const float* bih1 = (const float*)d_in[7];
    const float* bhh1 = (const float*)d_in[8];
    const float* Wfc  = (const float*)d_in[9];
    const float* bfc  = (const float*)d_in[10];

    lstm2_fused2<<<dim3(NBATCH / 256), dim3(512), 0, stream>>>(
        z, Wih0, Whh0, bih0, bhh0, Wih1, Whh1, bih1, bhh1, Wfc, bfc,
        (float*)d_out);
}